// Round 2
// baseline (74.355 us; speedup 1.0000x reference)
//
#include <hip/hip_runtime.h>
#include <hip/hip_bf16.h>

typedef __attribute__((ext_vector_type(8))) short short8;
typedef __attribute__((ext_vector_type(4))) float f32x4;

#define N_ENS 16
#define D_IN 784
#define D_HID 128
#define D_OUT 10
#define KPAD 800
#define NKT 25            // K tiles of 32 (784 padded to 800)
#define TILE_B 8192       // 128 cols x 32 k x 2B (bf16), fragment-packed
#define WS_B1 204800      // NKT*8192
#define WS_W2 205312      // + 128*4   (w2 stored [10][128] f32)
#define WS_B2 210432      // + 1280*4

// RNE float->bf16 (inputs are finite)
__device__ __forceinline__ unsigned short f2bf(float f) {
  unsigned int u = __float_as_uint(f);
  return (unsigned short)((u + 0x7FFFu + ((u >> 16) & 1u)) >> 16);
}

// ---------------- prep: combine ensemble -> ws ----------------
// w1 layout: [kt][col][kg][8 bf16]  addr = kt*8192 + col*64 + kg*16 + (k&7)*2
__global__ void prep_kernel(const float* __restrict__ fc_w, const float* __restrict__ fc_b,
                            const float* __restrict__ cls_w, const float* __restrict__ cls_b,
                            const float* __restrict__ factor, char* __restrict__ ws) {
  int tid = blockIdx.x * 256 + threadIdx.x;
  float f[N_ENS];
#pragma unroll
  for (int e = 0; e < N_ENS; ++e) f[e] = factor[e];

  if (tid < D_HID * KPAD) {                       // 102400: w1 bf16, fragment-packed
    int col = tid / KPAD;
    int k   = tid - col * KPAD;
    float v = 0.f;
    if (k < D_IN) {
#pragma unroll
      for (int e = 0; e < N_ENS; ++e) v += f[e] * fc_w[(size_t)(e * D_HID + col) * D_IN + k];
    }
    int kt = k >> 5, kk = k & 31;
    int byte = kt * TILE_B + col * 64 + ((kk >> 3) << 4) + ((kk & 7) << 1);
    *(unsigned short*)(ws + byte) = f2bf(v);
  } else if (tid < D_HID * KPAD + D_HID) {        // b1
    int col = tid - D_HID * KPAD;
    float v = 0.f;
#pragma unroll
    for (int e = 0; e < N_ENS; ++e) v += f[e] * fc_b[e * D_HID + col];
    *(float*)(ws + WS_B1 + col * 4) = v;
  } else if (tid < D_HID * KPAD + D_HID + D_HID * D_OUT) {  // w2o[o][n]
    int i = tid - (D_HID * KPAD + D_HID);
    int o = i >> 7, n = i & 127;
    float v = 0.f;
#pragma unroll
    for (int e = 0; e < N_ENS; ++e) v += f[e] * cls_w[(e * D_OUT + o) * D_HID + n];
    *(float*)(ws + WS_W2 + i * 4) = v;
  } else if (tid < D_HID * KPAD + D_HID + D_HID * D_OUT + D_OUT) {  // b2
    int o = tid - (D_HID * KPAD + D_HID + D_HID * D_OUT);
    float v = 0.f;
#pragma unroll
    for (int e = 0; e < N_ENS; ++e) v += f[e] * cls_b[e * D_OUT + o];
    *(float*)(ws + WS_B2 + o * 4) = v;
  }
}

// ---------------- main: barrier-free streaming GEMM1(relu) + GEMM2 ----------------
// 256 thr = 4 waves; wave w owns rows m0 + w*16 .. +16, all 128 cols (1x8 frags).
// No LDS / no barriers in the K-loop. One __syncthreads total (w2 staging).
__global__ __launch_bounds__(256, 4) void mnist_fused(const float* __restrict__ x,
                                                      const char* __restrict__ ws,
                                                      float* __restrict__ out) {
  __shared__ float h[64][132];   // epilogue only; wave-exclusive rows
  __shared__ float w2s[10][128];
  const int tid  = threadIdx.x;
  const int lane = tid & 63;
  const int w    = tid >> 6;
  const int l15  = lane & 15;
  const int kg   = lane >> 4;
  const int m0   = blockIdx.x * 64;

  // stage w2 -> LDS (the kernel's only barrier)
  {
    const float* w2g = (const float*)(ws + WS_W2);
    for (int i = tid; i < 1280; i += 256) ((float*)w2s)[i] = w2g[i];
  }
  __syncthreads();

  const float* ar = x + (size_t)(m0 + w * 16 + l15) * D_IN;  // this lane's A row
  const char*  bb = ws + l15 * 64 + kg * 16;                 // B frag base

  f32x4 acc[8];
#pragma unroll
  for (int ni = 0; ni < 8; ++ni) acc[ni] = f32x4{0.f, 0.f, 0.f, 0.f};

#pragma unroll 2
  for (int kt = 0; kt < 24; ++kt) {
    const float4 a0 = *(const float4*)(ar + kt * 32 + kg * 8);
    const float4 a1 = *(const float4*)(ar + kt * 32 + kg * 8 + 4);
    short8 b[8];
#pragma unroll
    for (int ni = 0; ni < 8; ++ni)
      b[ni] = *(const short8*)(bb + kt * TILE_B + ni * 1024);
    union { unsigned short u[8]; short8 s; } pk;
    pk.u[0] = f2bf(a0.x); pk.u[1] = f2bf(a0.y); pk.u[2] = f2bf(a0.z); pk.u[3] = f2bf(a0.w);
    pk.u[4] = f2bf(a1.x); pk.u[5] = f2bf(a1.y); pk.u[6] = f2bf(a1.z); pk.u[7] = f2bf(a1.w);
#pragma unroll
    for (int ni = 0; ni < 8; ++ni)
      acc[ni] = __builtin_amdgcn_mfma_f32_16x16x32_bf16(pk.s, b[ni], acc[ni], 0, 0, 0);
  }
  {  // tail kt=24: k 768..799, x valid only to 784 (kg>=2 -> A=0; B pre-zeroed)
    float4 a0 = float4{0.f, 0.f, 0.f, 0.f}, a1 = float4{0.f, 0.f, 0.f, 0.f};
    if (kg < 2) {
      a0 = *(const float4*)(ar + 768 + kg * 8);
      a1 = *(const float4*)(ar + 768 + kg * 8 + 4);
    }
    short8 b[8];
#pragma unroll
    for (int ni = 0; ni < 8; ++ni)
      b[ni] = *(const short8*)(bb + 24 * TILE_B + ni * 1024);
    union { unsigned short u[8]; short8 s; } pk;
    pk.u[0] = f2bf(a0.x); pk.u[1] = f2bf(a0.y); pk.u[2] = f2bf(a0.z); pk.u[3] = f2bf(a0.w);
    pk.u[4] = f2bf(a1.x); pk.u[5] = f2bf(a1.y); pk.u[6] = f2bf(a1.z); pk.u[7] = f2bf(a1.w);
#pragma unroll
    for (int ni = 0; ni < 8; ++ni)
      acc[ni] = __builtin_amdgcn_mfma_f32_16x16x32_bf16(pk.s, b[ni], acc[ni], 0, 0, 0);
  }

  // ---- epilogue 1: h = relu(acc + b1) -> LDS (rows w*16+kg*4+j, wave-exclusive)
  const float* b1g = (const float*)(ws + WS_B1);
#pragma unroll
  for (int ni = 0; ni < 8; ++ni) {
    const float bv = b1g[ni * 16 + l15];
#pragma unroll
    for (int j = 0; j < 4; ++j) {
      float v = acc[ni][j] + bv;
      h[w * 16 + kg * 4 + j][ni * 16 + l15] = v > 0.f ? v : 0.f;
    }
  }
  // no __syncthreads: epilogue 2 reads only rows this wave wrote (lgkmcnt ordering)

  // ---- epilogue 2: out = h @ w2^T + b2; lane handles row w*16+l15, n-quarter kg
  const int row = w * 16 + l15;
  float po[10];
#pragma unroll
  for (int o = 0; o < 10; ++o) po[o] = 0.f;
#pragma unroll
  for (int n4 = 0; n4 < 8; ++n4) {
    const float4 hv = *(const float4*)(&h[row][kg * 32 + n4 * 4]);
#pragma unroll
    for (int o = 0; o < 10; ++o) {
      const float4 wv = *(const float4*)(&w2s[o][kg * 32 + n4 * 4]);
      po[o] += hv.x * wv.x + hv.y * wv.y + hv.z * wv.z + hv.w * wv.w;
    }
  }
#pragma unroll
  for (int o = 0; o < 10; ++o) {
    po[o] += __shfl_xor(po[o], 16);
    po[o] += __shfl_xor(po[o], 32);
  }
  if (kg == 0) {
    const float* b2g = (const float*)(ws + WS_B2);
    float* op = out + (size_t)(m0 + row) * 10;
#pragma unroll
    for (int o = 0; o < 10; o += 2) {
      float2 v;
      v.x = po[o]     + b2g[o];
      v.y = po[o + 1] + b2g[o + 1];
      *(float2*)(op + o) = v;
    }
  }
}

extern "C" void kernel_launch(void* const* d_in, const int* in_sizes, int n_in,
                              void* d_out, int out_size, void* d_ws, size_t ws_size,
                              hipStream_t stream) {
  const float* x      = (const float*)d_in[0];
  const float* fc_w   = (const float*)d_in[1];
  const float* fc_b   = (const float*)d_in[2];
  const float* cls_w  = (const float*)d_in[3];
  const float* cls_b  = (const float*)d_in[4];
  const float* factor = (const float*)d_in[5];
  char* ws = (char*)d_ws;
  float* outp = (float*)d_out;

  prep_kernel<<<406, 256, 0, stream>>>(fc_w, fc_b, cls_w, cls_b, factor, ws);
  mnist_fused<<<1024, 256, 0, stream>>>(x, ws, outp);
}

// Round 3
// 49.238 us; speedup vs baseline: 1.5101x; 1.5101x over previous
//
#include <hip/hip_runtime.h>
#include <hip/hip_bf16.h>

typedef __attribute__((ext_vector_type(8))) short short8;
typedef __attribute__((ext_vector_type(4))) float f32x4;

#define N_ENS 16
#define D_IN 784
#define D_HID 128
#define D_OUT 10
#define KPAD 800
#define NKT 25            // K tiles of 32 (784 padded to 800)
#define TILE_B 8192       // 128 cols x 32 k x 2B (bf16), fragment-packed
#define WS_B1 204800      // NKT*8192
#define WS_W2 205312      // + 128*4   (w2 stored [10][128] f32)
#define WS_B2 210432      // + 1280*4

// RNE float->bf16 (inputs are finite)
__device__ __forceinline__ unsigned short f2bf(float f) {
  unsigned int u = __float_as_uint(f);
  return (unsigned short)((u + 0x7FFFu + ((u >> 16) & 1u)) >> 16);
}

__device__ __forceinline__ void gload_lds16(const void* g, void* l) {
  __builtin_amdgcn_global_load_lds((const __attribute__((address_space(1))) void*)g,
                                   (__attribute__((address_space(3))) void*)l, 16, 0, 0);
}

// ---------------- prep: combine ensemble -> ws ----------------
// w1 layout: [kt][col][kg][8 bf16]  addr = kt*8192 + col*64 + kg*16 + (k&7)*2
__global__ void prep_kernel(const float* __restrict__ fc_w, const float* __restrict__ fc_b,
                            const float* __restrict__ cls_w, const float* __restrict__ cls_b,
                            const float* __restrict__ factor, char* __restrict__ ws) {
  int tid = blockIdx.x * 256 + threadIdx.x;
  float f[N_ENS];
#pragma unroll
  for (int e = 0; e < N_ENS; ++e) f[e] = factor[e];

  if (tid < D_HID * KPAD) {                       // 102400: w1 bf16, fragment-packed
    int col = tid / KPAD;
    int k   = tid - col * KPAD;
    float v = 0.f;
    if (k < D_IN) {
#pragma unroll
      for (int e = 0; e < N_ENS; ++e) v += f[e] * fc_w[(size_t)(e * D_HID + col) * D_IN + k];
    }
    int kt = k >> 5, kk = k & 31;
    int byte = kt * TILE_B + col * 64 + ((kk >> 3) << 4) + ((kk & 7) << 1);
    *(unsigned short*)(ws + byte) = f2bf(v);
  } else if (tid < D_HID * KPAD + D_HID) {        // b1
    int col = tid - D_HID * KPAD;
    float v = 0.f;
#pragma unroll
    for (int e = 0; e < N_ENS; ++e) v += f[e] * fc_b[e * D_HID + col];
    *(float*)(ws + WS_B1 + col * 4) = v;
  } else if (tid < D_HID * KPAD + D_HID + D_HID * D_OUT) {  // w2o[o][n]
    int i = tid - (D_HID * KPAD + D_HID);
    int o = i >> 7, n = i & 127;
    float v = 0.f;
#pragma unroll
    for (int e = 0; e < N_ENS; ++e) v += f[e] * cls_w[(e * D_OUT + o) * D_HID + n];
    *(float*)(ws + WS_W2 + i * 4) = v;
  } else if (tid < D_HID * KPAD + D_HID + D_HID * D_OUT + D_OUT) {  // b2
    int o = tid - (D_HID * KPAD + D_HID + D_HID * D_OUT);
    float v = 0.f;
#pragma unroll
    for (int e = 0; e < N_ENS; ++e) v += f[e] * cls_b[e * D_OUT + o];
    *(float*)(ws + WS_B2 + o * 4) = v;
  }
}

// ---------------- main: counted-vmcnt pipelined GEMM1(relu) + GEMM2 ----------------
// 256 thr = 4 waves (4x1 grid): wave w owns rows m0+w*16..+16, all 128 cols.
// A: global->reg->bf16 (per-lane row). B: global_load_lds double-buffer,
// counted vmcnt(4) + raw 2-barrier per K-step (no vmcnt(0) drain in loop).
__global__ __launch_bounds__(256, 4) void mnist_fused(const float* __restrict__ x,
                                                      const char* __restrict__ ws,
                                                      float* __restrict__ out) {
  // LDS: B buffers @0..16K (2x8K); epilogue reuse: h f32 [64][132] @0 (33792B),
  // w2s @33792 (5120B). Total 38912 -> 4 blocks/CU.
  __shared__ __align__(16) char smem[38912];
  const int tid  = threadIdx.x;
  const int lane = tid & 63;
  const int w    = tid >> 6;
  const int l15  = lane & 15;
  const int kg   = lane >> 4;
  const int m0   = blockIdx.x * 64;

  const float* ar = x + (size_t)(m0 + w * 16 + l15) * D_IN;  // this lane's A row
  const int bfrag = l15 * 64 + kg * 16;                      // B frag offset in tile

  f32x4 acc[8];
#pragma unroll
  for (int ni = 0; ni < 8; ++ni) acc[ni] = f32x4{0.f, 0.f, 0.f, 0.f};

  // ---- prologue: stage B(0) into buf0, load A(0) to regs
  gload_lds16(ws + w * 2048 + lane * 16,        smem + w * 2048);
  gload_lds16(ws + w * 2048 + 1024 + lane * 16, smem + w * 2048 + 1024);
  float4 a0 = *(const float4*)(ar + kg * 8);
  float4 a1 = *(const float4*)(ar + kg * 8 + 4);

  for (int kt = 0; kt < NKT; ++kt) {
    const int cur = kt & 1;
    const int ktn = kt + 1;
    // (1) issue next B stage
    if (ktn < NKT) {
      const char* src = ws + ktn * TILE_B + w * 2048;
      char* dst = smem + (ktn & 1) * 8192 + w * 2048;
      gload_lds16(src + lane * 16, dst);
      gload_lds16(src + 1024 + lane * 16, dst + 1024);
    }
    // (2) convert A(kt) -> bf16 frag (compiler waits kt's A loads here)
    union { unsigned short u[8]; short8 s; } pk;
    pk.u[0] = f2bf(a0.x); pk.u[1] = f2bf(a0.y); pk.u[2] = f2bf(a0.z); pk.u[3] = f2bf(a0.w);
    pk.u[4] = f2bf(a1.x); pk.u[5] = f2bf(a1.y); pk.u[6] = f2bf(a1.z); pk.u[7] = f2bf(a1.w);
    // (3) load A(ktn) to regs
    if (ktn < NKT) {
      if (ktn < 24 || kg < 2) {   // x row ends at 784; k>=784 lanes -> zero (B is 0 there too)
        a0 = *(const float4*)(ar + ktn * 32 + kg * 8);
        a1 = *(const float4*)(ar + ktn * 32 + kg * 8 + 4);
      } else {
        a0 = float4{0.f, 0.f, 0.f, 0.f};
        a1 = float4{0.f, 0.f, 0.f, 0.f};
      }
      // (4) counted wait: drain kt's 4 VMEM, leave ktn's 4 in flight
      __builtin_amdgcn_sched_barrier(0);
      asm volatile("s_waitcnt vmcnt(4)" ::: "memory");
      __builtin_amdgcn_sched_barrier(0);
    } else {
      __builtin_amdgcn_sched_barrier(0);
      asm volatile("s_waitcnt vmcnt(0)" ::: "memory");
      __builtin_amdgcn_sched_barrier(0);
    }
    __builtin_amdgcn_s_barrier();              // B1: buf[cur] fully populated
    __builtin_amdgcn_sched_barrier(0);
    // (5) read B frags + MFMA
    {
      const char* Bb = smem + cur * 8192 + bfrag;
      short8 b[8];
#pragma unroll
      for (int ni = 0; ni < 8; ++ni) b[ni] = *(const short8*)(Bb + ni * 1024);
#pragma unroll
      for (int ni = 0; ni < 8; ++ni)
        acc[ni] = __builtin_amdgcn_mfma_f32_16x16x32_bf16(pk.s, b[ni], acc[ni], 0, 0, 0);
    }
    __builtin_amdgcn_sched_barrier(0);
    __builtin_amdgcn_s_barrier();              // B2: all reads of buf[cur] done
    __builtin_amdgcn_sched_barrier(0);
  }

  // ---- epilogue 1: h = relu(acc + b1) -> LDS (rows w*16+kg*4+j, wave-exclusive)
  const float* b1g = (const float*)(ws + WS_B1);
  float (*h)[132] = (float (*)[132])smem;
#pragma unroll
  for (int ni = 0; ni < 8; ++ni) {
    const float bv = b1g[ni * 16 + l15];
#pragma unroll
    for (int j = 0; j < 4; ++j) {
      float v = acc[ni][j] + bv;
      h[w * 16 + kg * 4 + j][ni * 16 + l15] = v > 0.f ? v : 0.f;
    }
  }
  // stage w2 -> LDS (region disjoint from h), then the kernel's only full sync
  float* w2s = (float*)(smem + 33792);
  {
    const float* w2g = (const float*)(ws + WS_W2);
    for (int i = tid; i < 1280; i += 256) w2s[i] = w2g[i];
  }
  __syncthreads();

  // ---- epilogue 2: out = h @ w2^T + b2; lane: row w*16+l15, n-quarter kg
  const int row = w * 16 + l15;
  float po[10];
#pragma unroll
  for (int o = 0; o < 10; ++o) po[o] = 0.f;
#pragma unroll
  for (int n4 = 0; n4 < 8; ++n4) {
    const float4 hv = *(const float4*)(&h[row][kg * 32 + n4 * 4]);
#pragma unroll
    for (int o = 0; o < 10; ++o) {
      const float4 wv = *(const float4*)(w2s + o * 128 + kg * 32 + n4 * 4);
      po[o] += hv.x * wv.x + hv.y * wv.y + hv.z * wv.z + hv.w * wv.w;
    }
  }
#pragma unroll
  for (int o = 0; o < 10; ++o) {
    po[o] += __shfl_xor(po[o], 16);
    po[o] += __shfl_xor(po[o], 32);
  }
  if (kg == 0) {
    const float* b2g = (const float*)(ws + WS_B2);
    float* op = out + (size_t)(m0 + row) * 10;
#pragma unroll
    for (int o = 0; o < 10; o += 2) {
      float2 v;
      v.x = po[o]     + b2g[o];
      v.y = po[o + 1] + b2g[o + 1];
      *(float2*)(op + o) = v;
    }
  }
}

extern "C" void kernel_launch(void* const* d_in, const int* in_sizes, int n_in,
                              void* d_out, int out_size, void* d_ws, size_t ws_size,
                              hipStream_t stream) {
  const float* x      = (const float*)d_in[0];
  const float* fc_w   = (const float*)d_in[1];
  const float* fc_b   = (const float*)d_in[2];
  const float* cls_w  = (const float*)d_in[3];
  const float* cls_b  = (const float*)d_in[4];
  const float* factor = (const float*)d_in[5];
  char* ws = (char*)d_ws;
  float* outp = (float*)d_out;

  prep_kernel<<<406, 256, 0, stream>>>(fc_w, fc_b, cls_w, cls_b, factor, ws);
  mnist_fused<<<1024, 256, 0, stream>>>(x, ws, outp);
}